// Round 4
// baseline (166.765 us; speedup 1.0000x reference)
//
#include <hip/hip_runtime.h>

#define N_ATOMS 50000
#define N_PAIRS 1600000
#define FDIM 128

typedef short short8 __attribute__((ext_vector_type(8)));
typedef float floatx4 __attribute__((ext_vector_type(4)));

// fp32 -> bf16 round-to-nearest-even
__device__ inline ushort f2bf(float f) {
    union { float f; unsigned u; } v; v.f = f;
    unsigned lsb = (v.u >> 16) & 1u;
    return (ushort)((v.u + 0x7fffu + lsb) >> 16);
}

// ---------------------------------------------------------------------------
// K1 "prep": one launch, three independent jobs selected by blockIdx:
//   [0, 3125)       x (1.6M float4) -> bf16, 2 float4/thread, coalesced
//   [3125, 3133)    W (4096 float4) -> bf16
//   [3133, 3329)    rowptr[i] = lower_bound(idx_i, i), i in [0, N_ATOMS]
// ---------------------------------------------------------------------------
#define XCONV_BLOCKS 3125
#define WCONV_BLOCKS 8
#define ROWPTR_BLOCKS 196
#define PREP_BLOCKS (XCONV_BLOCKS + WCONV_BLOCKS + ROWPTR_BLOCKS)

__global__ __launch_bounds__(256) void prep(const float* __restrict__ x,
                                            const float* __restrict__ W,
                                            const int* __restrict__ idx_i,
                                            ushort* __restrict__ xbf,
                                            ushort* __restrict__ wbf,
                                            int* __restrict__ rowptr) {
    const int b = blockIdx.x, t = threadIdx.x;
    if (b < XCONV_BLOCKS) {
        const int gid = b * 256 + t;                 // float4 id, [0, 800000)
#pragma unroll
        for (int k = 0; k < 2; ++k) {
            const int f4 = gid + k * (XCONV_BLOCKS * 256);
            const float4 v4 = ((const float4*)x)[f4];
            ushort4 o;
            o.x = f2bf(v4.x); o.y = f2bf(v4.y); o.z = f2bf(v4.z); o.w = f2bf(v4.w);
            ((ushort4*)xbf)[f4] = o;
        }
    } else if (b < XCONV_BLOCKS + WCONV_BLOCKS) {
        const int gid = (b - XCONV_BLOCKS) * 256 + t;  // [0, 2048)
#pragma unroll
        for (int k = 0; k < 2; ++k) {
            const int f4 = gid + k * 2048;
            const float4 v4 = ((const float4*)W)[f4];
            ushort4 o;
            o.x = f2bf(v4.x); o.y = f2bf(v4.y); o.z = f2bf(v4.z); o.w = f2bf(v4.w);
            ((ushort4*)wbf)[f4] = o;
        }
    } else {
        const int i = (b - XCONV_BLOCKS - WCONV_BLOCKS) * 256 + t;
        if (i > N_ATOMS) return;
        int lo = 0, hi = N_PAIRS;
        while (lo < hi) {
            int mid = (lo + hi) >> 1;
            if (idx_i[mid] < i) lo = mid + 1; else hi = mid;
        }
        rowptr[i] = lo;
    }
}

// ---------------------------------------------------------------------------
// K2: z[i,:] = sum_p alpha[p] * xbf[idx_j[p],:]   (fp32, written to d_out)
// One wave per atom. Batches of 8 pairs: 8 uniform scalar (j,alpha) loads
// (masked clamp -> no serial tail), 8 independent dword gathers in flight,
// then 16 FMAs. Lane l holds features 2l,2l+1 (256 B coalesced row read).
// ---------------------------------------------------------------------------
__global__ __launch_bounds__(256) void scatter_z(const ushort* __restrict__ xbf,
                                                 const float* __restrict__ alpha,
                                                 const int* __restrict__ idx_j,
                                                 const int* __restrict__ rowptr,
                                                 float* __restrict__ z) {
    const int lane = threadIdx.x & 63;
    const int atom = blockIdx.x * 4 + (threadIdx.x >> 6);
    if (atom >= N_ATOMS) return;

    const int start = __builtin_amdgcn_readfirstlane(rowptr[atom]);
    const int end   = __builtin_amdgcn_readfirstlane(rowptr[atom + 1]);

    float ax = 0.f, ay = 0.f;
    const ushort* vb = xbf + 2 * lane;

    for (int p = start; p < end; p += 8) {
        int jj[8]; float aa[8];
#pragma unroll
        for (int u = 0; u < 8; ++u) {
            const int pp = p + u;
            const int pc = pp < end ? pp : (end - 1);   // clamped (end>start here)
            jj[u] = idx_j[pc];
            aa[u] = pp < end ? alpha[pp] : 0.f;
        }
        unsigned vv[8];
#pragma unroll
        for (int u = 0; u < 8; ++u)
            vv[u] = *(const unsigned*)(vb + (long)jj[u] * FDIM);
#pragma unroll
        for (int u = 0; u < 8; ++u) {
            ax += aa[u] * __uint_as_float(vv[u] << 16);
            ay += aa[u] * __uint_as_float(vv[u] & 0xffff0000u);
        }
    }
    *(float2*)(z + (long)atom * FDIM + 2 * lane) = make_float2(ax, ay);
}

// ---------------------------------------------------------------------------
// K3: y = z @ Wbf^T, IN PLACE on d_out. Block = 256 thr (4 waves), 64 rows.
// Each wave reads its own 16-row strip into A-frags (registers, vmcnt-gated
// before first MFMA), then overwrites the same strip -> race-free in place.
// Wbf staged to LDS stride-136 shorts (2-way bank alias = free).
// A: lane m=lane&15, k=8*(lane>>4)+j ; D: col=lane&15, row=4*(lane>>4)+r.
// ---------------------------------------------------------------------------
__global__ __launch_bounds__(256) void gemm_zwt(const ushort* __restrict__ wbf,
                                                float* __restrict__ y) {
    __shared__ ushort Wsh[128 * 136];
    const int t = threadIdx.x;

#pragma unroll
    for (int u = 0; u < 8; ++u) {
        const int id = t + 256 * u;      // [0, 2048) short8-chunks
        const int f = id >> 4;
        const int c = id & 15;
        const short8 w8 = *(const short8*)(wbf + f * FDIM + 8 * c);
        *(short8*)&Wsh[f * 136 + 8 * c] = w8;
    }
    __syncthreads();

    const int lane = t & 63, wv = t >> 6;
    const int mrow = lane & 15, q = lane >> 4;
    const int mw = blockIdx.x * 64 + wv * 16;

    int row = mw + mrow;
    if (row >= N_ATOMS) row = N_ATOMS - 1;   // clamped reads; stores guarded
    const float* zr = y + (long)row * FDIM + 8 * q;

    short8 a[4];
#pragma unroll
    for (int kc = 0; kc < 4; ++kc) {
        const float4 lo4 = *(const float4*)(zr + 32 * kc);
        const float4 hi4 = *(const float4*)(zr + 32 * kc + 4);
        short8 af;
        af[0] = f2bf(lo4.x); af[1] = f2bf(lo4.y); af[2] = f2bf(lo4.z); af[3] = f2bf(lo4.w);
        af[4] = f2bf(hi4.x); af[5] = f2bf(hi4.y); af[6] = f2bf(hi4.z); af[7] = f2bf(hi4.w);
        a[kc] = af;
    }

    floatx4 acc[8];
#pragma unroll
    for (int f = 0; f < 8; ++f) acc[f] = (floatx4)(0.f);

#pragma unroll
    for (int f = 0; f < 8; ++f) {
        const ushort* wr = &Wsh[(16 * f + mrow) * 136 + 8 * q];
#pragma unroll
        for (int kc = 0; kc < 4; ++kc)
            acc[f] = __builtin_amdgcn_mfma_f32_16x16x32_bf16(a[kc], *(const short8*)(wr + 32 * kc), acc[f], 0, 0, 0);
    }

#pragma unroll
    for (int f = 0; f < 8; ++f) {
#pragma unroll
        for (int r = 0; r < 4; ++r) {
            const int orow = mw + 4 * q + r;
            if (orow < N_ATOMS)
                y[(long)orow * FDIM + 16 * f + mrow] = acc[f][r];
        }
    }
}

extern "C" void kernel_launch(void* const* d_in, const int* in_sizes, int n_in,
                              void* d_out, int out_size, void* d_ws, size_t ws_size,
                              hipStream_t stream) {
    const float* x     = (const float*)d_in[0];
    const float* alpha = (const float*)d_in[1];
    const int*   idx_i = (const int*)d_in[2];   // int32 per harness contract
    const int*   idx_j = (const int*)d_in[3];
    const float* W     = (const float*)d_in[4];
    float* y = (float*)d_out;

    // ws layout: xbf 12.8 MB | wbf 32 KB | rowptr 200 KB  (~13.03 MB total)
    ushort* xbf    = (ushort*)d_ws;
    ushort* wbf    = (ushort*)((char*)d_ws + (size_t)N_ATOMS * FDIM * 2);
    int*    rowptr = (int*)((char*)wbf + (size_t)FDIM * FDIM * 2);

    prep<<<PREP_BLOCKS, 256, 0, stream>>>(x, W, idx_i, xbf, wbf, rowptr);
    scatter_z<<<(N_ATOMS + 3) / 4, 256, 0, stream>>>(xbf, alpha, idx_j, rowptr, y);
    gemm_zwt<<<(N_ATOMS + 63) / 64, 256, 0, stream>>>(wbf, y);
}

// Round 5
// 157.601 us; speedup vs baseline: 1.0581x; 1.0581x over previous
//
#include <hip/hip_runtime.h>

#define N_ATOMS 50000
#define N_PAIRS 1600000
#define FDIM 128

typedef short short8 __attribute__((ext_vector_type(8)));
typedef float floatx4 __attribute__((ext_vector_type(4)));

// fp32 -> bf16 round-to-nearest-even
__device__ inline ushort f2bf(float f) {
    union { float f; unsigned u; } v; v.f = f;
    unsigned lsb = (v.u >> 16) & 1u;
    return (ushort)((v.u + 0x7fffu + lsb) >> 16);
}
__device__ inline float bflo(unsigned u) { return __uint_as_float(u << 16); }
__device__ inline float bfhi(unsigned u) { return __uint_as_float(u & 0xffff0000u); }

// ---------------------------------------------------------------------------
// K1 "prep": one launch, three independent jobs selected by blockIdx:
//   [0, 3125)       x (1.6M float4) -> bf16
//   [3125, 3133)    W (4096 float4) -> bf16
//   [3133, 3329)    rowptr[i] = lower_bound(idx_i, i), i in [0, N_ATOMS]
// ---------------------------------------------------------------------------
#define XCONV_BLOCKS 3125
#define WCONV_BLOCKS 8
#define ROWPTR_BLOCKS 196
#define PREP_BLOCKS (XCONV_BLOCKS + WCONV_BLOCKS + ROWPTR_BLOCKS)

__global__ __launch_bounds__(256) void prep(const float* __restrict__ x,
                                            const float* __restrict__ W,
                                            const int* __restrict__ idx_i,
                                            ushort* __restrict__ xbf,
                                            ushort* __restrict__ wbf,
                                            int* __restrict__ rowptr) {
    const int b = blockIdx.x, t = threadIdx.x;
    if (b < XCONV_BLOCKS) {
        const int gid = b * 256 + t;
#pragma unroll
        for (int k = 0; k < 2; ++k) {
            const int f4 = gid + k * (XCONV_BLOCKS * 256);
            const float4 v4 = ((const float4*)x)[f4];
            ushort4 o;
            o.x = f2bf(v4.x); o.y = f2bf(v4.y); o.z = f2bf(v4.z); o.w = f2bf(v4.w);
            ((ushort4*)xbf)[f4] = o;
        }
    } else if (b < XCONV_BLOCKS + WCONV_BLOCKS) {
        const int gid = (b - XCONV_BLOCKS) * 256 + t;
#pragma unroll
        for (int k = 0; k < 2; ++k) {
            const int f4 = gid + k * 2048;
            const float4 v4 = ((const float4*)W)[f4];
            ushort4 o;
            o.x = f2bf(v4.x); o.y = f2bf(v4.y); o.z = f2bf(v4.z); o.w = f2bf(v4.w);
            ((ushort4*)wbf)[f4] = o;
        }
    } else {
        const int i = (b - XCONV_BLOCKS - WCONV_BLOCKS) * 256 + t;
        if (i > N_ATOMS) return;
        int lo = 0, hi = N_PAIRS;
        while (lo < hi) {
            int mid = (lo + hi) >> 1;
            if (idx_i[mid] < i) lo = mid + 1; else hi = mid;
        }
        rowptr[i] = lo;
    }
}

// ---------------------------------------------------------------------------
// K2: z[i,:] = sum_p alpha[p] * xbf[idx_j[p],:]  (fp32, into d_out)
// One wave per atom; lane = (g = pair-subgroup 0..3) x (c = 16B chunk 0..15).
// One global_load_dwordx4 gathers FOUR rows (1 KB) per instruction; j/alpha
// are per-lane vector loads (4 distinct dwords, L1 broadcast). Unroll 4 ->
// up to 4 KB outstanding per wave. Epilogue: shfl-xor(16,32) cross-group
// reduce + one fully-coalesced 512 B float2 store (lane owns feats 8c+2g).
// ---------------------------------------------------------------------------
__global__ __launch_bounds__(256) void scatter_z(const ushort* __restrict__ xbf,
                                                 const float* __restrict__ alpha,
                                                 const int* __restrict__ idx_j,
                                                 const int* __restrict__ rowptr,
                                                 float* __restrict__ z) {
    const int lane = threadIdx.x & 63;
    const int atom = blockIdx.x * 4 + (threadIdx.x >> 6);
    if (atom >= N_ATOMS) return;
    const int g = lane >> 4;
    const int c = lane & 15;

    const int start = __builtin_amdgcn_readfirstlane(rowptr[atom]);
    const int end   = __builtin_amdgcn_readfirstlane(rowptr[atom + 1]);

    float acc[8];
#pragma unroll
    for (int k = 0; k < 8; ++k) acc[k] = 0.f;

    const ushort* xc = xbf + 8 * c;

#pragma unroll 4
    for (int p0 = start; p0 < end; p0 += 4) {
        const int  pp    = p0 + g;
        const bool valid = pp < end;
        const int  pc    = valid ? pp : start;      // start < end inside loop
        const int  j     = idx_j[pc];
        float      a     = alpha[pc];
        a = valid ? a : 0.f;
        const uint4 vv = *(const uint4*)(xc + (long)j * FDIM);
        acc[0] += a * bflo(vv.x); acc[1] += a * bfhi(vv.x);
        acc[2] += a * bflo(vv.y); acc[3] += a * bfhi(vv.y);
        acc[4] += a * bflo(vv.z); acc[5] += a * bfhi(vv.z);
        acc[6] += a * bflo(vv.w); acc[7] += a * bfhi(vv.w);
    }

    // reduce the 4 pair-subgroups (lanes differing in bits 4,5)
#pragma unroll
    for (int k = 0; k < 8; ++k) {
        acc[k] += __shfl_xor(acc[k], 16);
        acc[k] += __shfl_xor(acc[k], 32);
    }

    // lane stores features 8c+2g, 8c+2g+1 -> 64 lanes x 8B = 512 B coalesced
    const float e0 = (g & 1) ? acc[2] : acc[0];
    const float e1 = (g & 1) ? acc[3] : acc[1];
    const float f0 = (g & 1) ? acc[6] : acc[4];
    const float f1 = (g & 1) ? acc[7] : acc[5];
    float2 o;
    o.x = (g & 2) ? f0 : e0;
    o.y = (g & 2) ? f1 : e1;
    *(float2*)(z + (long)atom * FDIM + 8 * c + 2 * g) = o;
}

// ---------------------------------------------------------------------------
// K3: y = z @ Wbf^T, IN PLACE on d_out. Block = 256 thr (4 waves), 64 rows.
// Each wave reads its own 16-row strip into A-frags before overwriting it.
// Wbf staged to LDS stride-136 shorts (2-way bank alias = free).
// A: m=lane&15, k=8*(lane>>4)+j ; D: col=lane&15, row=4*(lane>>4)+r.
// ---------------------------------------------------------------------------
__global__ __launch_bounds__(256) void gemm_zwt(const ushort* __restrict__ wbf,
                                                float* __restrict__ y) {
    __shared__ ushort Wsh[128 * 136];
    const int t = threadIdx.x;

#pragma unroll
    for (int u = 0; u < 8; ++u) {
        const int id = t + 256 * u;
        const int f = id >> 4;
        const int c = id & 15;
        *(short8*)&Wsh[f * 136 + 8 * c] = *(const short8*)(wbf + f * FDIM + 8 * c);
    }
    __syncthreads();

    const int lane = t & 63, wv = t >> 6;
    const int mrow = lane & 15, q = lane >> 4;
    const int mw = blockIdx.x * 64 + wv * 16;

    int row = mw + mrow;
    if (row >= N_ATOMS) row = N_ATOMS - 1;   // clamped reads; stores guarded
    const float* zr = y + (long)row * FDIM + 8 * q;

    short8 a[4];
#pragma unroll
    for (int kc = 0; kc < 4; ++kc) {
        const float4 lo4 = *(const float4*)(zr + 32 * kc);
        const float4 hi4 = *(const float4*)(zr + 32 * kc + 4);
        short8 af;
        af[0] = f2bf(lo4.x); af[1] = f2bf(lo4.y); af[2] = f2bf(lo4.z); af[3] = f2bf(lo4.w);
        af[4] = f2bf(hi4.x); af[5] = f2bf(hi4.y); af[6] = f2bf(hi4.z); af[7] = f2bf(hi4.w);
        a[kc] = af;
    }

    floatx4 acc[8];
#pragma unroll
    for (int f = 0; f < 8; ++f) acc[f] = (floatx4)(0.f);

#pragma unroll
    for (int f = 0; f < 8; ++f) {
        const ushort* wr = &Wsh[(16 * f + mrow) * 136 + 8 * q];
#pragma unroll
        for (int kc = 0; kc < 4; ++kc)
            acc[f] = __builtin_amdgcn_mfma_f32_16x16x32_bf16(a[kc], *(const short8*)(wr + 32 * kc), acc[f], 0, 0, 0);
    }

#pragma unroll
    for (int f = 0; f < 8; ++f) {
#pragma unroll
        for (int r = 0; r < 4; ++r) {
            const int orow = mw + 4 * q + r;
            if (orow < N_ATOMS)
                y[(long)orow * FDIM + 16 * f + mrow] = acc[f][r];
        }
    }
}

extern "C" void kernel_launch(void* const* d_in, const int* in_sizes, int n_in,
                              void* d_out, int out_size, void* d_ws, size_t ws_size,
                              hipStream_t stream) {
    const float* x     = (const float*)d_in[0];
    const float* alpha = (const float*)d_in[1];
    const int*   idx_i = (const int*)d_in[2];   // int32 per harness contract
    const int*   idx_j = (const int*)d_in[3];
    const float* W     = (const float*)d_in[4];
    float* y = (float*)d_out;

    // ws layout: xbf 12.8 MB | wbf 32 KB | rowptr 200 KB
    ushort* xbf    = (ushort*)d_ws;
    ushort* wbf    = (ushort*)((char*)d_ws + (size_t)N_ATOMS * FDIM * 2);
    int*    rowptr = (int*)((char*)wbf + (size_t)FDIM * FDIM * 2);

    prep<<<PREP_BLOCKS, 256, 0, stream>>>(x, W, idx_i, xbf, wbf, rowptr);
    scatter_z<<<(N_ATOMS + 3) / 4, 256, 0, stream>>>(xbf, alpha, idx_j, rowptr, y);
    gemm_zwt<<<(N_ATOMS + 63) / 64, 256, 0, stream>>>(wbf, y);
}

// Round 6
// 150.781 us; speedup vs baseline: 1.1060x; 1.0452x over previous
//
#include <hip/hip_runtime.h>

#define N_ATOMS 50000
#define N_PAIRS 1600000
#define FDIM 128

typedef short short8 __attribute__((ext_vector_type(8)));
typedef float floatx4 __attribute__((ext_vector_type(4)));

// fp32 -> bf16 round-to-nearest-even
__device__ inline ushort f2bf(float f) {
    union { float f; unsigned u; } v; v.f = f;
    unsigned lsb = (v.u >> 16) & 1u;
    return (ushort)((v.u + 0x7fffu + lsb) >> 16);
}
__device__ inline float bflo(unsigned u) { return __uint_as_float(u << 16); }
__device__ inline float bfhi(unsigned u) { return __uint_as_float(u & 0xffff0000u); }

#define GEMM_BLOCKS 782   // ceil(50000/64) rows
#define RP_BLOCKS   196   // ceil(50001/256)

// ---------------------------------------------------------------------------
// K1: fused (independent jobs by blockIdx):
//   [0, 782):    v = bf16(x @ W^T) via mfma_f32_16x16x32_bf16 (r3-verified)
//   [782, 978):  rowptr[i] = lower_bound(idx_i, i)
// ---------------------------------------------------------------------------
__global__ __launch_bounds__(256) void gemm_rowptr(const float* __restrict__ x,
                                                   const float* __restrict__ W,
                                                   const int* __restrict__ idx_i,
                                                   ushort* __restrict__ v,
                                                   int* __restrict__ rowptr) {
    const int t = threadIdx.x;
    if (blockIdx.x >= GEMM_BLOCKS) {
        const int i = (blockIdx.x - GEMM_BLOCKS) * 256 + t;
        if (i > N_ATOMS) return;
        int lo = 0, hi = N_PAIRS;
        while (lo < hi) {
            int mid = (lo + hi) >> 1;
            if (idx_i[mid] < i) lo = mid + 1; else hi = mid;
        }
        rowptr[i] = lo;
        return;
    }

    __shared__ ushort Wsh[128 * 136];
    // stage W (128x128 fp32 -> bf16): 4096 float4, 16 per thread
#pragma unroll
    for (int u = 0; u < 16; ++u) {
        int id = t + 256 * u;
        int f  = id >> 5;
        int k4 = (id & 31) * 4;
        const float4 w4 = *(const float4*)(W + f * FDIM + k4);
        ushort* d = &Wsh[f * 136 + k4];
        d[0] = f2bf(w4.x); d[1] = f2bf(w4.y); d[2] = f2bf(w4.z); d[3] = f2bf(w4.w);
    }
    __syncthreads();

    const int lane = t & 63, wv = t >> 6;
    const int mrow = lane & 15, q = lane >> 4;
    const int mw   = blockIdx.x * 64 + wv * 16;

    int row = mw + mrow;
    if (row >= N_ATOMS) row = N_ATOMS - 1;   // clamped reads; stores guarded
    const float* xr = x + (long)row * FDIM + 8 * q;

    short8 a[4];
#pragma unroll
    for (int kc = 0; kc < 4; ++kc) {
        const float4 lo4 = *(const float4*)(xr + 32 * kc);
        const float4 hi4 = *(const float4*)(xr + 32 * kc + 4);
        short8 af;
        af[0] = f2bf(lo4.x); af[1] = f2bf(lo4.y); af[2] = f2bf(lo4.z); af[3] = f2bf(lo4.w);
        af[4] = f2bf(hi4.x); af[5] = f2bf(hi4.y); af[6] = f2bf(hi4.z); af[7] = f2bf(hi4.w);
        a[kc] = af;
    }

    floatx4 acc[8];
#pragma unroll
    for (int f = 0; f < 8; ++f) acc[f] = (floatx4)(0.f);

#pragma unroll
    for (int f = 0; f < 8; ++f) {
        const ushort* wr = &Wsh[(16 * f + mrow) * 136 + 8 * q];
#pragma unroll
        for (int kc = 0; kc < 4; ++kc)
            acc[f] = __builtin_amdgcn_mfma_f32_16x16x32_bf16(a[kc], *(const short8*)(wr + 32 * kc), acc[f], 0, 0, 0);
    }

    // D: col = lane&15 (feature 16f+mrow), row = mw + 4q + r -> bf16 store
#pragma unroll
    for (int f = 0; f < 8; ++f) {
#pragma unroll
        for (int r = 0; r < 4; ++r) {
            const int orow = mw + 4 * q + r;
            if (orow < N_ATOMS)
                v[(long)orow * FDIM + 16 * f + mrow] = f2bf(acc[f][r]);
        }
    }
}

// ---------------------------------------------------------------------------
// K2: y[i,:] = sum_p alpha[p] * v[idx_j[p],:]  written directly (no atomics,
// no memset). One wave handles 4 CONSECUTIVE atoms (contiguous idx/alpha
// stream, warm pipeline across atom boundaries). lane = (g 0..3) x (c 0..15);
// one dwordx4 gathers 4 rows (1 KB/instr); unroll-8 keeps TWO gathers in
// flight (2 KB/wave). 32-bit byte offsets (j<<8) minimize address VALU.
// Epilogue: shfl-xor(16,32) reduce + 512 B coalesced float2 store.
// ---------------------------------------------------------------------------
__global__ __launch_bounds__(256) void scatter_y(const ushort* __restrict__ v,
                                                 const float* __restrict__ alpha,
                                                 const int* __restrict__ idx_j,
                                                 const int* __restrict__ rowptr,
                                                 float* __restrict__ y) {
    const int lane = threadIdx.x & 63;
    const int wave = blockIdx.x * 4 + (threadIdx.x >> 6);   // [0, 12500)
    const int g = lane >> 4;
    const int c = lane & 15;
    const char* vbase = (const char*)v + (c << 4);

    const int a0 = wave * 4;                                // 4*12500 == N_ATOMS
    int s = __builtin_amdgcn_readfirstlane(rowptr[a0]);

    for (int k = 0; k < 4; ++k) {
        const int atom = a0 + k;
        const int e = __builtin_amdgcn_readfirstlane(rowptr[atom + 1]);

        float acc[8];
#pragma unroll
        for (int u = 0; u < 8; ++u) acc[u] = 0.f;

        for (int p0 = s; p0 < e; p0 += 8) {
            const int pa = p0 + g;
            const int pb = p0 + 4 + g;
            const bool va = pa < e;
            const bool vb = pb < e;
            const int pca = va ? pa : s;       // s < e inside this loop
            const int pcb = vb ? pb : s;
            const int ja = idx_j[pca];
            const int jb = idx_j[pcb];
            float aa = alpha[pca]; if (!va) aa = 0.f;
            float ab = alpha[pcb]; if (!vb) ab = 0.f;
            const uint4 u4a = *(const uint4*)(vbase + ((unsigned)ja << 8));
            const uint4 u4b = *(const uint4*)(vbase + ((unsigned)jb << 8));
            acc[0] += aa * bflo(u4a.x); acc[1] += aa * bfhi(u4a.x);
            acc[2] += aa * bflo(u4a.y); acc[3] += aa * bfhi(u4a.y);
            acc[4] += aa * bflo(u4a.z); acc[5] += aa * bfhi(u4a.z);
            acc[6] += aa * bflo(u4a.w); acc[7] += aa * bfhi(u4a.w);
            acc[0] += ab * bflo(u4b.x); acc[1] += ab * bfhi(u4b.x);
            acc[2] += ab * bflo(u4b.y); acc[3] += ab * bfhi(u4b.y);
            acc[4] += ab * bflo(u4b.z); acc[5] += ab * bfhi(u4b.z);
            acc[6] += ab * bflo(u4b.w); acc[7] += ab * bfhi(u4b.w);
        }

        // reduce across the 4 pair-subgroups (lane bits 4,5)
#pragma unroll
        for (int u = 0; u < 8; ++u) {
            acc[u] += __shfl_xor(acc[u], 16);
            acc[u] += __shfl_xor(acc[u], 32);
        }

        // lane stores feats 8c+2g, 8c+2g+1 -> 64 lanes x 8 B = 512 B
        const float e0 = (g & 1) ? acc[2] : acc[0];
        const float e1 = (g & 1) ? acc[3] : acc[1];
        const float f0 = (g & 1) ? acc[6] : acc[4];
        const float f1 = (g & 1) ? acc[7] : acc[5];
        float2 o;
        o.x = (g & 2) ? f0 : e0;
        o.y = (g & 2) ? f1 : e1;
        *(float2*)(y + (long)atom * FDIM + 8 * c + 2 * g) = o;

        s = e;
    }
}

extern "C" void kernel_launch(void* const* d_in, const int* in_sizes, int n_in,
                              void* d_out, int out_size, void* d_ws, size_t ws_size,
                              hipStream_t stream) {
    const float* x     = (const float*)d_in[0];
    const float* alpha = (const float*)d_in[1];
    const int*   idx_i = (const int*)d_in[2];   // int32 per harness contract
    const int*   idx_j = (const int*)d_in[3];
    const float* W     = (const float*)d_in[4];
    float* y = (float*)d_out;

    // ws layout: v 12.8 MB | rowptr 200 KB
    ushort* v      = (ushort*)d_ws;
    int*    rowptr = (int*)((char*)d_ws + (size_t)N_ATOMS * FDIM * 2);

    gemm_rowptr<<<GEMM_BLOCKS + RP_BLOCKS, 256, 0, stream>>>(x, W, idx_i, v, rowptr);
    scatter_y<<<(N_ATOMS / 16), 256, 0, stream>>>(v, alpha, idx_j, rowptr, y);
}

// Round 7
// 146.501 us; speedup vs baseline: 1.1383x; 1.0292x over previous
//
#include <hip/hip_runtime.h>

#define N_ATOMS 50000
#define N_PAIRS 1600000
#define FDIM 128

typedef short short8 __attribute__((ext_vector_type(8)));
typedef float floatx4 __attribute__((ext_vector_type(4)));

// fp32 -> bf16 round-to-nearest-even
__device__ inline ushort f2bf(float f) {
    union { float f; unsigned u; } v; v.f = f;
    unsigned lsb = (v.u >> 16) & 1u;
    return (ushort)((v.u + 0x7fffu + lsb) >> 16);
}
__device__ inline float bflo(unsigned u) { return __uint_as_float(u << 16); }
__device__ inline float bfhi(unsigned u) { return __uint_as_float(u & 0xffff0000u); }

#define GEMM_BLOCKS 782   // ceil(50000/64) rows
#define RP_BLOCKS   196   // ceil(50001/256)

// ---------------------------------------------------------------------------
// K1: fused (independent jobs by blockIdx):
//   [0, 782):    v = bf16(x @ W^T) via mfma_f32_16x16x32_bf16
//   [782, 978):  rowptr[i] = lower_bound(idx_i, i)
// ---------------------------------------------------------------------------
__global__ __launch_bounds__(256) void gemm_rowptr(const float* __restrict__ x,
                                                   const float* __restrict__ W,
                                                   const int* __restrict__ idx_i,
                                                   ushort* __restrict__ v,
                                                   int* __restrict__ rowptr) {
    const int t = threadIdx.x;
    if (blockIdx.x >= GEMM_BLOCKS) {
        const int i = (blockIdx.x - GEMM_BLOCKS) * 256 + t;
        if (i > N_ATOMS) return;
        int lo = 0, hi = N_PAIRS;
        while (lo < hi) {
            int mid = (lo + hi) >> 1;
            if (idx_i[mid] < i) lo = mid + 1; else hi = mid;
        }
        rowptr[i] = lo;
        return;
    }

    __shared__ ushort Wsh[128 * 136];
#pragma unroll
    for (int u = 0; u < 16; ++u) {
        int id = t + 256 * u;
        int f  = id >> 5;
        int k4 = (id & 31) * 4;
        const float4 w4 = *(const float4*)(W + f * FDIM + k4);
        ushort* d = &Wsh[f * 136 + k4];
        d[0] = f2bf(w4.x); d[1] = f2bf(w4.y); d[2] = f2bf(w4.z); d[3] = f2bf(w4.w);
    }
    __syncthreads();

    const int lane = t & 63, wv = t >> 6;
    const int mrow = lane & 15, q = lane >> 4;
    const int mw   = blockIdx.x * 64 + wv * 16;

    int row = mw + mrow;
    if (row >= N_ATOMS) row = N_ATOMS - 1;   // clamped reads; stores guarded
    const float* xr = x + (long)row * FDIM + 8 * q;

    short8 a[4];
#pragma unroll
    for (int kc = 0; kc < 4; ++kc) {
        const float4 lo4 = *(const float4*)(xr + 32 * kc);
        const float4 hi4 = *(const float4*)(xr + 32 * kc + 4);
        short8 af;
        af[0] = f2bf(lo4.x); af[1] = f2bf(lo4.y); af[2] = f2bf(lo4.z); af[3] = f2bf(lo4.w);
        af[4] = f2bf(hi4.x); af[5] = f2bf(hi4.y); af[6] = f2bf(hi4.z); af[7] = f2bf(hi4.w);
        a[kc] = af;
    }

    floatx4 acc[8];
#pragma unroll
    for (int f = 0; f < 8; ++f) acc[f] = (floatx4)(0.f);

#pragma unroll
    for (int f = 0; f < 8; ++f) {
        const ushort* wr = &Wsh[(16 * f + mrow) * 136 + 8 * q];
#pragma unroll
        for (int kc = 0; kc < 4; ++kc)
            acc[f] = __builtin_amdgcn_mfma_f32_16x16x32_bf16(a[kc], *(const short8*)(wr + 32 * kc), acc[f], 0, 0, 0);
    }

#pragma unroll
    for (int f = 0; f < 8; ++f) {
#pragma unroll
        for (int r = 0; r < 4; ++r) {
            const int orow = mw + 4 * q + r;
            if (orow < N_ATOMS)
                v[(long)orow * FDIM + 16 * f + mrow] = f2bf(acc[f][r]);
        }
    }
}

// ---------------------------------------------------------------------------
// K2: y[i,:] = sum_p alpha[p] * v[idx_j[p],:]  (fp32, direct, no atomics).
// ONE ATOM PER WAVE (50000 waves — max TLP; r5's proven-fastest shape).
// lane = (g = pair-subgroup 0..3) x (c = 16B chunk 0..15): one dwordx4
// gathers FOUR rows (1 KB/instr); j/alpha are per-lane vector loads.
// pragma unroll 8 lets the compiler pipeline up to 8 gathers (8 KB) per
// wave. Epilogue: shfl-xor(16,32) reduce + 512 B coalesced float2 store.
// ---------------------------------------------------------------------------
__global__ __launch_bounds__(256) void scatter_y(const ushort* __restrict__ v,
                                                 const float* __restrict__ alpha,
                                                 const int* __restrict__ idx_j,
                                                 const int* __restrict__ rowptr,
                                                 float* __restrict__ y) {
    const int lane = threadIdx.x & 63;
    const int atom = blockIdx.x * 4 + (threadIdx.x >> 6);
    if (atom >= N_ATOMS) return;
    const int g = lane >> 4;
    const int c = lane & 15;
    const char* vbase = (const char*)v + (c << 4);

    const int start = __builtin_amdgcn_readfirstlane(rowptr[atom]);
    const int end   = __builtin_amdgcn_readfirstlane(rowptr[atom + 1]);

    float acc[8];
#pragma unroll
    for (int k = 0; k < 8; ++k) acc[k] = 0.f;

#pragma unroll 8
    for (int p0 = start; p0 < end; p0 += 4) {
        const int  pp    = p0 + g;
        const bool valid = pp < end;
        const int  pc    = valid ? pp : start;      // start < end inside loop
        const int  j     = idx_j[pc];
        float      a     = alpha[pc];
        a = valid ? a : 0.f;
        const uint4 vv = *(const uint4*)(vbase + ((unsigned)j << 8));
        acc[0] += a * bflo(vv.x); acc[1] += a * bfhi(vv.x);
        acc[2] += a * bflo(vv.y); acc[3] += a * bfhi(vv.y);
        acc[4] += a * bflo(vv.z); acc[5] += a * bfhi(vv.z);
        acc[6] += a * bflo(vv.w); acc[7] += a * bfhi(vv.w);
    }

    // reduce the 4 pair-subgroups (lane bits 4,5)
#pragma unroll
    for (int k = 0; k < 8; ++k) {
        acc[k] += __shfl_xor(acc[k], 16);
        acc[k] += __shfl_xor(acc[k], 32);
    }

    // lane stores feats 8c+2g, 8c+2g+1 -> 64 lanes x 8 B = 512 B coalesced
    const float e0 = (g & 1) ? acc[2] : acc[0];
    const float e1 = (g & 1) ? acc[3] : acc[1];
    const float f0 = (g & 1) ? acc[6] : acc[4];
    const float f1 = (g & 1) ? acc[7] : acc[5];
    float2 o;
    o.x = (g & 2) ? f0 : e0;
    o.y = (g & 2) ? f1 : e1;
    *(float2*)(y + (long)atom * FDIM + 8 * c + 2 * g) = o;
}

extern "C" void kernel_launch(void* const* d_in, const int* in_sizes, int n_in,
                              void* d_out, int out_size, void* d_ws, size_t ws_size,
                              hipStream_t stream) {
    const float* x     = (const float*)d_in[0];
    const float* alpha = (const float*)d_in[1];
    const int*   idx_i = (const int*)d_in[2];   // int32 per harness contract
    const int*   idx_j = (const int*)d_in[3];
    const float* W     = (const float*)d_in[4];
    float* y = (float*)d_out;

    // ws layout: v 12.8 MB | rowptr 200 KB
    ushort* v      = (ushort*)d_ws;
    int*    rowptr = (int*)((char*)d_ws + (size_t)N_ATOMS * FDIM * 2);

    gemm_rowptr<<<GEMM_BLOCKS + RP_BLOCKS, 256, 0, stream>>>(x, W, idx_i, v, rowptr);
    scatter_y<<<(N_ATOMS + 3) / 4, 256, 0, stream>>>(v, alpha, idx_j, rowptr, y);
}